// Round 8
// baseline (111.774 us; speedup 1.0000x reference)
//
#include <hip/hip_runtime.h>

#define NBINS 256
#define NCH 3
#define NWAVES 4              // 256 threads / 64 lanes
#define BLOCK 256
#define HSIZE (NCH * NBINS)   // 768
#define ELEMS_PER_THREAD 12   // 3 x float4; 12 % 3 == 0 so channel is compile-time
#define BLOCKS_PER_BATCH 32

// Fused: hist blocks store partials to ws; the last-arriving block per batch
// (mod-32 counter -> works for ANY initial counter value, so no memset needed,
// replay-safe) reduces the 32 partials and writes the final output.
__global__ __launch_bounds__(BLOCK) void hist_fused(const float* __restrict__ in,
                                                    unsigned int* __restrict__ partials,
                                                    unsigned int* __restrict__ cnt,
                                                    float* __restrict__ out,
                                                    int floatsPerBatch,
                                                    float inv_n) {
    __shared__ unsigned int h[NWAVES][HSIZE];   // 12 KB
    __shared__ int isLast;

    const int tid = threadIdx.x;
    for (int i = tid; i < NWAVES * HSIZE; i += BLOCK) ((unsigned int*)h)[i] = 0u;
    __syncthreads();

    const int b     = blockIdx.x / BLOCKS_PER_BATCH;
    const int chunk = blockIdx.x % BLOCKS_PER_BATCH;
    const int chunkFloats = floatsPerBatch / BLOCKS_PER_BATCH;    // 24576
    const float* base = in + (size_t)b * floatsPerBatch + (size_t)chunk * chunkFloats;
    const int w = tid >> 6;

    const int floatsPerIter = BLOCK * ELEMS_PER_THREAD;           // 3072
    const int iters = chunkFloats / floatsPerIter;                // 8

    for (int it = 0; it < iters; ++it) {
        const float4* p = (const float4*)(base + (size_t)it * floatsPerIter
                                               + (size_t)tid * ELEMS_PER_THREAD);
        float4 v0 = p[0];
        float4 v1 = p[1];
        float4 v2 = p[2];
        float v[ELEMS_PER_THREAD] = {v0.x, v0.y, v0.z, v0.w,
                                     v1.x, v1.y, v1.z, v1.w,
                                     v2.x, v2.y, v2.z, v2.w};
#pragma unroll
        for (int j = 0; j < ELEMS_PER_THREAD; ++j) {
            int bin = (int)(v[j] * 256.0f);                 // v>=0: trunc == floor
            bin = bin < 0 ? 0 : (bin > NBINS - 1 ? NBINS - 1 : bin);
            const int c = j % NCH;                          // compile-time under unroll
            atomicAdd(&h[w][c * NBINS + bin], 1u);
        }
    }
    __syncthreads();

    // store this block's partial histogram (coalesced, plain stores)
    unsigned int* dst = partials + (size_t)blockIdx.x * HSIZE;
    for (int i = tid; i < HSIZE; i += BLOCK) {
        dst[i] = h[0][i] + h[1][i] + h[2][i] + h[3][i];
    }

    // release our stores, then signal completion
    __threadfence();
    __syncthreads();
    if (tid == 0) {
        unsigned int old = atomicAdd(&cnt[b], 1u);
        // 32 increments hit each residue mod 32 exactly once -> exactly one
        // winner regardless of the counter's starting value (poison/replays).
        isLast = ((old + 1u) % BLOCKS_PER_BATCH == 0u) ? 1 : 0;
    }
    __syncthreads();

    if (isLast) {
        __threadfence();   // acquire: make all 32 partials visible
        const unsigned int* p = partials + (size_t)b * BLOCKS_PER_BATCH * HSIZE;
        // 256 threads x 3 slots each; exact u32 sums; scale by 2^-18 (exact)
        for (int i = tid; i < HSIZE; i += BLOCK) {
            unsigned int s = 0;
#pragma unroll
            for (int ch = 0; ch < BLOCKS_PER_BATCH; ++ch) s += p[(size_t)ch * HSIZE + i];
            const int c   = i >> 8;
            const int bin = i & (NBINS - 1);
            out[(size_t)b * HSIZE + bin * NCH + c] = (float)s * inv_n;
        }
    }
}

// Fallback path (ws too small): pre-zeroed out + exact float atomics.
__global__ __launch_bounds__(BLOCK) void hist_atomic(const float* __restrict__ in,
                                                     float* __restrict__ out,
                                                     int floatsPerBatch,
                                                     float inv_n) {
    __shared__ unsigned int h[NWAVES][HSIZE];
    const int tid = threadIdx.x;
    for (int i = tid; i < NWAVES * HSIZE; i += BLOCK) ((unsigned int*)h)[i] = 0u;
    __syncthreads();

    const int b     = blockIdx.x / BLOCKS_PER_BATCH;
    const int chunk = blockIdx.x % BLOCKS_PER_BATCH;
    const int chunkFloats = floatsPerBatch / BLOCKS_PER_BATCH;
    const float* base = in + (size_t)b * floatsPerBatch + (size_t)chunk * chunkFloats;
    const int w = tid >> 6;
    const int floatsPerIter = BLOCK * ELEMS_PER_THREAD;
    const int iters = chunkFloats / floatsPerIter;

    for (int it = 0; it < iters; ++it) {
        const float4* p = (const float4*)(base + (size_t)it * floatsPerIter
                                               + (size_t)tid * ELEMS_PER_THREAD);
        float4 v0 = p[0], v1 = p[1], v2 = p[2];
        float v[ELEMS_PER_THREAD] = {v0.x, v0.y, v0.z, v0.w,
                                     v1.x, v1.y, v1.z, v1.w,
                                     v2.x, v2.y, v2.z, v2.w};
#pragma unroll
        for (int j = 0; j < ELEMS_PER_THREAD; ++j) {
            int bin = (int)(v[j] * 256.0f);
            bin = bin < 0 ? 0 : (bin > NBINS - 1 ? NBINS - 1 : bin);
            const int c = j % NCH;
            atomicAdd(&h[w][c * NBINS + bin], 1u);
        }
    }
    __syncthreads();
    float* dst = out + (size_t)b * HSIZE;
    for (int i = tid; i < HSIZE; i += BLOCK) {
        unsigned int s = h[0][i] + h[1][i] + h[2][i] + h[3][i];
        if (s) {
            const int c   = i >> 8;
            const int bin = i & (NBINS - 1);
            atomicAdd(&dst[bin * NCH + c], (float)s * inv_n);
        }
    }
}

extern "C" void kernel_launch(void* const* d_in, const int* in_sizes, int n_in,
                              void* d_out, int out_size, void* d_ws, size_t ws_size,
                              hipStream_t stream) {
    const float* in = (const float*)d_in[0];
    float* out = (float*)d_out;

    const int floatsPerBatch = 512 * 512 * 3;        // H*W*C
    const int total = in_sizes[0];
    const int B = total / floatsPerBatch;            // 32
    const float inv_n = 1.0f / (float)(512 * 512);   // 2^-18, exact

    const size_t partialsBytes = (size_t)B * BLOCKS_PER_BATCH * HSIZE * sizeof(unsigned int);
    const size_t wsNeeded = partialsBytes + (size_t)B * sizeof(unsigned int);

    if (ws_size >= wsNeeded) {
        unsigned int* partials = (unsigned int*)d_ws;
        unsigned int* cnt = (unsigned int*)((char*)d_ws + partialsBytes);
        hist_fused<<<B * BLOCKS_PER_BATCH, BLOCK, 0, stream>>>(
            in, partials, cnt, out, floatsPerBatch, inv_n);
    } else {
        hipMemsetAsync(d_out, 0, (size_t)out_size * sizeof(float), stream);
        hist_atomic<<<B * BLOCKS_PER_BATCH, BLOCK, 0, stream>>>(
            in, out, floatsPerBatch, inv_n);
    }
}

// Round 9
// 26.374 us; speedup vs baseline: 4.2380x; 4.2380x over previous
//
#include <hip/hip_runtime.h>

#define NBINS 256
#define NCH 3
#define NWAVES 4              // 256 threads / 64 lanes
#define BLOCK 256
#define HSIZE (NCH * NBINS)   // 768
#define ELEMS_PER_THREAD 12   // 3 x float4; 12 % 3 == 0 so channel is compile-time

// R6-identical hist loop; BLOCKS_PER_BATCH is now a template parameter so we
// can pick grid granularity by available ws. Partial histograms -> plain
// coalesced stores (no memset, no atomics); tiny reduce kernel finishes.
template <bool USE_WS, int BPB>
__global__ __launch_bounds__(BLOCK) void hist_kernel(const float* __restrict__ in,
                                                     unsigned int* __restrict__ ws,
                                                     float* __restrict__ out,
                                                     int floatsPerBatch,
                                                     float inv_n) {
    __shared__ unsigned int h[NWAVES][HSIZE];   // 12 KB

    const int tid = threadIdx.x;
    for (int i = tid; i < NWAVES * HSIZE; i += BLOCK) ((unsigned int*)h)[i] = 0u;
    __syncthreads();

    const int b     = blockIdx.x / BPB;
    const int chunk = blockIdx.x % BPB;
    const int chunkFloats = floatsPerBatch / BPB;
    const float* base = in + (size_t)b * floatsPerBatch + (size_t)chunk * chunkFloats;
    const int w = tid >> 6;

    const int floatsPerIter = BLOCK * ELEMS_PER_THREAD;           // 3072
    const int iters = chunkFloats / floatsPerIter;                // 8 (BPB=32) / 4 (BPB=64)

    const float4* p0 = (const float4*)(base + (size_t)tid * ELEMS_PER_THREAD);
    float4 a0 = p0[0], a1 = p0[1], a2 = p0[2];    // prefetch iter 0

#pragma unroll
    for (int it = 0; it < (768 / ELEMS_PER_THREAD / (BPB / 32) / 8) * 8 / 8 + 0; ++it) {
        // (kept simple below; see loop over iters)
        break;
    }

    for (int it = 0; it < iters; ++it) {
        float4 b0, b1, b2;
        if (it + 1 < iters) {
            const float4* pn = (const float4*)((const float*)p0 + (size_t)(it + 1) * floatsPerIter);
            b0 = pn[0]; b1 = pn[1]; b2 = pn[2];
        }
        float v[ELEMS_PER_THREAD] = {a0.x, a0.y, a0.z, a0.w,
                                     a1.x, a1.y, a1.z, a1.w,
                                     a2.x, a2.y, a2.z, a2.w};
#pragma unroll
        for (int j = 0; j < ELEMS_PER_THREAD; ++j) {
            int bin = (int)(v[j] * 256.0f);                 // v>=0: trunc == floor
            bin = bin < 0 ? 0 : (bin > NBINS - 1 ? NBINS - 1 : bin);
            const int c = j % NCH;                          // compile-time under unroll
            atomicAdd(&h[w][c * NBINS + bin], 1u);
        }
        a0 = b0; a1 = b1; a2 = b2;
    }
    __syncthreads();

    if (USE_WS) {
        unsigned int* dst = ws + (size_t)blockIdx.x * HSIZE;
        for (int i = tid; i < HSIZE; i += BLOCK) {
            dst[i] = h[0][i] + h[1][i] + h[2][i] + h[3][i];
        }
    } else {
        float* dst = out + (size_t)b * HSIZE;
        for (int i = tid; i < HSIZE; i += BLOCK) {
            unsigned int s = h[0][i] + h[1][i] + h[2][i] + h[3][i];
            if (s) {
                const int c   = i >> 8;
                const int bin = i & (NBINS - 1);
                atomicAdd(&dst[bin * NCH + c], (float)s * inv_n);
            }
        }
    }
}

// One block per batch x 768 threads; tid = c*256 + bin. Coalesced, exact sums.
template <int BPB>
__global__ __launch_bounds__(HSIZE) void reduce_kernel(const unsigned int* __restrict__ ws,
                                                       float* __restrict__ out,
                                                       float inv_n) {
    const int b = blockIdx.x;
    const int t = threadIdx.x;
    const unsigned int* p = ws + (size_t)b * BPB * HSIZE + t;
    unsigned int s = 0;
#pragma unroll
    for (int ch = 0; ch < BPB; ++ch) s += p[(size_t)ch * HSIZE];
    const int c   = t >> 8;
    const int bin = t & (NBINS - 1);
    out[(size_t)b * HSIZE + bin * NCH + c] = (float)s * inv_n;
}

extern "C" void kernel_launch(void* const* d_in, const int* in_sizes, int n_in,
                              void* d_out, int out_size, void* d_ws, size_t ws_size,
                              hipStream_t stream) {
    const float* in = (const float*)d_in[0];
    float* out = (float*)d_out;

    const int floatsPerBatch = 512 * 512 * 3;        // H*W*C
    const int total = in_sizes[0];
    const int B = total / floatsPerBatch;            // 32
    const float inv_n = 1.0f / (float)(512 * 512);   // 2^-18, exact

    const size_t ws64 = (size_t)B * 64 * HSIZE * sizeof(unsigned int);   // 6 MB
    const size_t ws32 = (size_t)B * 32 * HSIZE * sizeof(unsigned int);   // 3 MB

    if (ws_size >= ws64) {
        unsigned int* ws = (unsigned int*)d_ws;
        hist_kernel<true, 64><<<B * 64, BLOCK, 0, stream>>>(in, ws, out, floatsPerBatch, inv_n);
        reduce_kernel<64><<<B, HSIZE, 0, stream>>>(ws, out, inv_n);
    } else if (ws_size >= ws32) {
        unsigned int* ws = (unsigned int*)d_ws;
        hist_kernel<true, 32><<<B * 32, BLOCK, 0, stream>>>(in, ws, out, floatsPerBatch, inv_n);
        reduce_kernel<32><<<B, HSIZE, 0, stream>>>(ws, out, inv_n);
    } else {
        hipMemsetAsync(d_out, 0, (size_t)out_size * sizeof(float), stream);
        hist_kernel<false, 32><<<B * 32, BLOCK, 0, stream>>>(in, nullptr, out,
                                                             floatsPerBatch, inv_n);
    }
}

// Round 10
// 23.303 us; speedup vs baseline: 4.7967x; 1.1318x over previous
//
#include <hip/hip_runtime.h>

#define NBINS 256
#define NCH 3
#define NWAVES 4              // 256 threads / 64 lanes
#define BLOCK 256
#define HSIZE (NCH * NBINS)   // 768
#define ELEMS_PER_THREAD 12   // 3 x float4; 12 % 3 == 0 so channel is compile-time

// R6-identical hist loop; BPB (blocks per batch) selects grid granularity.
// Partial histograms -> plain coalesced stores (no memset, no atomics);
// tiny reduce kernel finishes.
template <bool USE_WS, int BPB>
__global__ __launch_bounds__(BLOCK) void hist_kernel(const float* __restrict__ in,
                                                     unsigned int* __restrict__ ws,
                                                     float* __restrict__ out,
                                                     int floatsPerBatch,
                                                     float inv_n) {
    __shared__ unsigned int h[NWAVES][HSIZE];   // 12 KB

    const int tid = threadIdx.x;
    for (int i = tid; i < NWAVES * HSIZE; i += BLOCK) ((unsigned int*)h)[i] = 0u;
    __syncthreads();

    const int b     = blockIdx.x / BPB;
    const int chunk = blockIdx.x % BPB;
    const int chunkFloats = floatsPerBatch / BPB;                 // 49152 (BPB=16)
    const float* base = in + (size_t)b * floatsPerBatch + (size_t)chunk * chunkFloats;
    const int w = tid >> 6;

    const int floatsPerIter = BLOCK * ELEMS_PER_THREAD;           // 3072
    const int iters = chunkFloats / floatsPerIter;                // 16 (BPB=16)

    const float4* p0 = (const float4*)(base + (size_t)tid * ELEMS_PER_THREAD);
    float4 a0 = p0[0], a1 = p0[1], a2 = p0[2];    // prefetch iter 0

    for (int it = 0; it < iters; ++it) {
        float4 b0, b1, b2;
        if (it + 1 < iters) {
            const float4* pn = (const float4*)((const float*)p0 + (size_t)(it + 1) * floatsPerIter);
            b0 = pn[0]; b1 = pn[1]; b2 = pn[2];   // next-iter loads in flight
        }
        float v[ELEMS_PER_THREAD] = {a0.x, a0.y, a0.z, a0.w,
                                     a1.x, a1.y, a1.z, a1.w,
                                     a2.x, a2.y, a2.z, a2.w};
#pragma unroll
        for (int j = 0; j < ELEMS_PER_THREAD; ++j) {
            int bin = (int)(v[j] * 256.0f);                 // v>=0: trunc == floor
            bin = bin < 0 ? 0 : (bin > NBINS - 1 ? NBINS - 1 : bin);
            const int c = j % NCH;                          // compile-time under unroll
            atomicAdd(&h[w][c * NBINS + bin], 1u);
        }
        a0 = b0; a1 = b1; a2 = b2;
    }
    __syncthreads();

    if (USE_WS) {
        unsigned int* dst = ws + (size_t)blockIdx.x * HSIZE;
        for (int i = tid; i < HSIZE; i += BLOCK) {
            dst[i] = h[0][i] + h[1][i] + h[2][i] + h[3][i];
        }
    } else {
        float* dst = out + (size_t)b * HSIZE;
        for (int i = tid; i < HSIZE; i += BLOCK) {
            unsigned int s = h[0][i] + h[1][i] + h[2][i] + h[3][i];
            if (s) {
                const int c   = i >> 8;
                const int bin = i & (NBINS - 1);
                atomicAdd(&dst[bin * NCH + c], (float)s * inv_n);
            }
        }
    }
}

// One block per batch x 768 threads; tid = c*256 + bin. Coalesced, exact sums.
template <int BPB>
__global__ __launch_bounds__(HSIZE) void reduce_kernel(const unsigned int* __restrict__ ws,
                                                       float* __restrict__ out,
                                                       float inv_n) {
    const int b = blockIdx.x;
    const int t = threadIdx.x;
    const unsigned int* p = ws + (size_t)b * BPB * HSIZE + t;
    unsigned int s = 0;
#pragma unroll
    for (int ch = 0; ch < BPB; ++ch) s += p[(size_t)ch * HSIZE];
    const int c   = t >> 8;
    const int bin = t & (NBINS - 1);
    out[(size_t)b * HSIZE + bin * NCH + c] = (float)s * inv_n;
}

extern "C" void kernel_launch(void* const* d_in, const int* in_sizes, int n_in,
                              void* d_out, int out_size, void* d_ws, size_t ws_size,
                              hipStream_t stream) {
    const float* in = (const float*)d_in[0];
    float* out = (float*)d_out;

    const int floatsPerBatch = 512 * 512 * 3;        // H*W*C
    const int total = in_sizes[0];
    const int B = total / floatsPerBatch;            // 32
    const float inv_n = 1.0f / (float)(512 * 512);   // 2^-18, exact

    const size_t ws16 = (size_t)B * 16 * HSIZE * sizeof(unsigned int);   // 1.5 MB
    const size_t ws32 = (size_t)B * 32 * HSIZE * sizeof(unsigned int);   // 3 MB

    if (ws_size >= ws16) {
        unsigned int* ws = (unsigned int*)d_ws;
        hist_kernel<true, 16><<<B * 16, BLOCK, 0, stream>>>(in, ws, out, floatsPerBatch, inv_n);
        reduce_kernel<16><<<B, HSIZE, 0, stream>>>(ws, out, inv_n);
    } else if (ws_size >= ws32) {   // unreachable ordering kept for clarity
        unsigned int* ws = (unsigned int*)d_ws;
        hist_kernel<true, 32><<<B * 32, BLOCK, 0, stream>>>(in, ws, out, floatsPerBatch, inv_n);
        reduce_kernel<32><<<B, HSIZE, 0, stream>>>(ws, out, inv_n);
    } else {
        hipMemsetAsync(d_out, 0, (size_t)out_size * sizeof(float), stream);
        hist_kernel<false, 32><<<B * 32, BLOCK, 0, stream>>>(in, nullptr, out,
                                                             floatsPerBatch, inv_n);
    }
}